// Round 6
// baseline (698.452 us; speedup 1.0000x reference)
//
#include <hip/hip_runtime.h>
#include <math.h>

#define NNODES 50000
#define NEDGES 1600000
#define DIM    128
#define NHID   (NNODES * DIM)      // 6,400,000
#define TPB    256
#define NTILES ((NNODES + 63) / 64)   // 782, 64 rows per block-tile

// binned CSR build
#define NBINS  196                 // ceil(50000/256)
#define BINSZ  256                 // nodes per bin (dst>>8)
#define EPT    16                  // edges per thread in binning passes
#define CHUNK  (TPB * EPT)         // 4096 edges per block
#define NCHUNKS ((NEDGES + CHUNK - 1) / CHUNK)   // 391
#define BINCAP 10240               // staged edges per bin (mean 8192, sigma 90)

typedef unsigned short bf16_t;
typedef __attribute__((ext_vector_type(8))) short short8;   // 8 bf16, 4 VGPRs
typedef __attribute__((ext_vector_type(4))) float f32x4;    // MFMA acc

__device__ __forceinline__ float bf_lo(unsigned u) { return __uint_as_float(u << 16); }
__device__ __forceinline__ float bf_hi(unsigned u) { return __uint_as_float(u & 0xFFFF0000u); }
__device__ __forceinline__ bf16_t f2bf(float f) {   // RNE
    unsigned u = __float_as_uint(f);
    u += 0x7FFFu + ((u >> 16) & 1u);
    return (bf16_t)(u >> 16);
}
__device__ __forceinline__ unsigned pack2bf(float a, float b) {
    return (unsigned)f2bf(a) | ((unsigned)f2bf(b) << 16);
}

union S8U { short8 v; uint4 u4; unsigned us[4]; };

// ===========================================================================
// CSR build, dense-write pipeline (round-2 proven):
//   bin_hist -> bin_scan -> bin_scatter (packed dl<<16|src) -> build_csr
//   (per-bin LDS counting sort -> per-node off[] + sorted src bucket).
// ===========================================================================
__global__ __launch_bounds__(TPB) void bin_hist_kernel(
    const int* __restrict__ dst, int* __restrict__ gcnt)
{
    __shared__ int lcnt[NBINS];
    const int tid = threadIdx.x;
    for (int i = tid; i < NBINS; i += TPB) lcnt[i] = 0;
    __syncthreads();
    const int base = blockIdx.x * CHUNK;
    #pragma unroll
    for (int k = 0; k < EPT; ++k) {
        int e = base + k * TPB + tid;
        if (e < NEDGES) atomicAdd(&lcnt[dst[e] >> 8], 1);
    }
    __syncthreads();
    for (int i = tid; i < NBINS; i += TPB) {
        int c = lcnt[i];
        if (c) atomicAdd(&gcnt[i], c);
    }
}

__global__ __launch_bounds__(64) void bin_scan_kernel(
    const int* __restrict__ gcnt, int* __restrict__ start, int* __restrict__ bcur,
    int* __restrict__ off)
{
    const int lane = threadIdx.x;   // 64 lanes, each owns 4 bins
    int c[4];
    int s = 0;
    #pragma unroll
    for (int k = 0; k < 4; ++k) {
        int b = 4 * lane + k;
        c[k] = (b < NBINS) ? gcnt[b] : 0;
        s += c[k];
    }
    int incl = s;
    #pragma unroll
    for (int d = 1; d < 64; d <<= 1) {
        int t = __shfl_up(incl, d);
        if (lane >= d) incl += t;
    }
    int excl = incl - s;
    #pragma unroll
    for (int k = 0; k < 4; ++k) {
        int b = 4 * lane + k;
        if (b < NBINS) { start[b] = excl; bcur[b] = excl; }
        excl += c[k];
    }
    if (lane == 63) { start[NBINS] = excl; off[NNODES] = excl; }   // == NEDGES
}

__global__ __launch_bounds__(TPB) void bin_scatter_kernel(
    const int* __restrict__ src, const int* __restrict__ dst,
    int* __restrict__ bcur, unsigned* __restrict__ bucket)
{
    __shared__ int lcnt[NBINS];    // phase A: counts
    __shared__ int lcur[NBINS];    // phase C: absolute cursors
    const int tid = threadIdx.x;
    for (int i = tid; i < NBINS; i += TPB) lcnt[i] = 0;
    __syncthreads();

    unsigned pk[EPT];
    int bn[EPT];
    const int base = blockIdx.x * CHUNK;
    #pragma unroll
    for (int k = 0; k < EPT; ++k) {
        int e = base + k * TPB + tid;
        int b = -1; unsigned p = 0;
        if (e < NEDGES) {
            int d = dst[e];
            int s = src[e];
            b = d >> 8;
            p = ((unsigned)(d & 255) << 16) | (unsigned)s;
            atomicAdd(&lcnt[b], 1);
        }
        pk[k] = p; bn[k] = b;
    }
    __syncthreads();
    for (int i = tid; i < NBINS; i += TPB) {
        int c = lcnt[i];
        lcur[i] = (c > 0) ? atomicAdd(&bcur[i], c) : 0;
    }
    __syncthreads();
    #pragma unroll
    for (int k = 0; k < EPT; ++k) {
        if (bn[k] >= 0) {
            int p = atomicAdd(&lcur[bn[k]], 1);
            bucket[p] = pk[k];
        }
    }
}

__global__ __launch_bounds__(TPB) void build_csr_kernel(
    const int* __restrict__ start, unsigned* __restrict__ bucket,
    int* __restrict__ off)
{
    __shared__ unsigned se[BINCAP];   // staged bin edges, 40 KB
    __shared__ int lcnt[BINSZ];
    __shared__ int lofs[BINSZ];
    __shared__ int wsum[4];
    const int tid = threadIdx.x;
    const int b = blockIdx.x;
    const int j0 = start[b], j1 = start[b + 1];
    const int n = j1 - j0;            // <= BINCAP by construction

    lcnt[tid] = 0;
    for (int i = tid; i < n; i += TPB) se[i] = bucket[j0 + i];
    __syncthreads();
    for (int i = tid; i < n; i += TPB) atomicAdd(&lcnt[se[i] >> 16], 1);
    __syncthreads();

    // exclusive scan of lcnt[256] across 4 waves
    const int lane = tid & 63, wid = tid >> 6;
    int v = lcnt[tid];
    int s = v;
    #pragma unroll
    for (int d = 1; d < 64; d <<= 1) {
        int t = __shfl_up(s, d);
        if (lane >= d) s += t;
    }
    if (lane == 63) wsum[wid] = s;
    __syncthreads();
    if (tid == 0) {
        int a = 0;
        #pragma unroll
        for (int k = 0; k < 4; ++k) { int t = wsum[k]; wsum[k] = a; a += t; }
    }
    __syncthreads();
    int excl = wsum[wid] + s - v;
    lofs[tid] = excl;
    int node = b * BINSZ + tid;
    if (node < NNODES) off[node] = j0 + excl;
    __syncthreads();

    // in-place counting-sort scatter (safe: all edges staged in LDS)
    for (int i = tid; i < n; i += TPB) {
        unsigned e = se[i];
        int pos = atomicAdd(&lofs[e >> 16], 1);
        bucket[j0 + pos] = e & 0xFFFFu;   // src node id
    }
}

// ---------------------------------------------------------------------------
// Gather aggregation, wave per node, 16/8/1-deep ILP (latency-bound: more
// outstanding bytes per wave). gather_cat reads the full contiguous 512B
// h_cat row with ONE wave-wide uint2 load (lanes 0-31 = mean half, lanes
// 32-63 = std half); float4 store at 4*lane maps onto [mean128|std128].
// ---------------------------------------------------------------------------
__global__ __launch_bounds__(TPB) void gather_agg_f32_kernel(
    const float* __restrict__ h, const int* __restrict__ off,
    const unsigned* __restrict__ bucket, float* __restrict__ acat)
{
    int node = blockIdx.x * (TPB / 64) + (threadIdx.x >> 6);
    int lane = threadIdx.x & 63;
    if (node >= NNODES) return;
    int j0 = off[node], j1 = off[node + 1];
    const float* base = h + 2 * lane;
    float ax = 0.0f, ay = 0.0f;
    int j = j0;
    for (; j + 16 <= j1; j += 16) {
        unsigned s[16];
        #pragma unroll
        for (int k = 0; k < 16; ++k) s[k] = bucket[j + k];
        float2 v[16];
        #pragma unroll
        for (int k = 0; k < 16; ++k) v[k] = *(const float2*)(base + (size_t)s[k] * DIM);
        #pragma unroll
        for (int k = 0; k < 16; ++k) { ax += v[k].x; ay += v[k].y; }
    }
    for (; j + 8 <= j1; j += 8) {
        unsigned s[8];
        #pragma unroll
        for (int k = 0; k < 8; ++k) s[k] = bucket[j + k];
        float2 v[8];
        #pragma unroll
        for (int k = 0; k < 8; ++k) v[k] = *(const float2*)(base + (size_t)s[k] * DIM);
        #pragma unroll
        for (int k = 0; k < 8; ++k) { ax += v[k].x; ay += v[k].y; }
    }
    for (; j < j1; ++j) {
        float2 v0 = *(const float2*)(base + (size_t)bucket[j] * DIM);
        ax += v0.x; ay += v0.y;
    }
    *(float2*)(acat + (size_t)node * 256 + 2 * lane) = make_float2(ax, ay);
}

__global__ __launch_bounds__(TPB) void gather_cat_kernel(
    const bf16_t* __restrict__ hc, const int* __restrict__ off,
    const unsigned* __restrict__ bucket, float* __restrict__ acat)
{
    int node = blockIdx.x * (TPB / 64) + (threadIdx.x >> 6);
    int lane = threadIdx.x & 63;
    if (node >= NNODES) return;
    int j0 = off[node], j1 = off[node + 1];
    const uint2* base = (const uint2*)hc + lane;   // 64 uint2 per 512B row
    float a0 = 0.f, a1 = 0.f, a2 = 0.f, a3 = 0.f;
    int j = j0;
    for (; j + 16 <= j1; j += 16) {
        unsigned s[16];
        #pragma unroll
        for (int k = 0; k < 16; ++k) s[k] = bucket[j + k];
        uint2 u[16];
        #pragma unroll
        for (int k = 0; k < 16; ++k) u[k] = base[(size_t)s[k] * 64];
        #pragma unroll
        for (int k = 0; k < 16; ++k) {
            a0 += bf_lo(u[k].x); a1 += bf_hi(u[k].x);
            a2 += bf_lo(u[k].y); a3 += bf_hi(u[k].y);
        }
    }
    for (; j + 8 <= j1; j += 8) {
        unsigned s[8];
        #pragma unroll
        for (int k = 0; k < 8; ++k) s[k] = bucket[j + k];
        uint2 u[8];
        #pragma unroll
        for (int k = 0; k < 8; ++k) u[k] = base[(size_t)s[k] * 64];
        #pragma unroll
        for (int k = 0; k < 8; ++k) {
            a0 += bf_lo(u[k].x); a1 += bf_hi(u[k].x);
            a2 += bf_lo(u[k].y); a3 += bf_hi(u[k].y);
        }
    }
    for (; j < j1; ++j) {
        uint2 u = base[(size_t)bucket[j] * 64];
        a0 += bf_lo(u.x); a1 += bf_hi(u.x);
        a2 += bf_lo(u.y); a3 += bf_hi(u.y);
    }
    // lane<32: mean cols 4l..4l+3 -> acat[4l..]; lane>=32: std cols -> 128+...
    *(float4*)(acat + (size_t)node * 256 + 4 * lane) = make_float4(a0, a1, a2, a3);
}

// ---------------------------------------------------------------------------
// FUSED GIN layer, both paths in one grid (block path = blockIdx/NTILES):
//   out_half = sigmoid(z@W1+b1)@W2+b2, z = (1+eps)*hin_half + agg_half.
//   W1/W2 staged bf16 in LDS; W1 frags hoisted to VGPRs; y1 f32 overlays
//   the W1 LDS region; MFMA2 A from y1 (same RNE point -> bit-identical to
//   a global bf16 round-trip), B from W2 LDS. SPLIT hi/lo on z.
//   h_cat layout: row stride 256 bf16, path half = p*128. In-place safe.
// ---------------------------------------------------------------------------
template <class HinT, int INSTRIDE>
__global__ __launch_bounds__(TPB, 2) void fused_layer_kernel(
    const HinT* __restrict__ hin, const float* __restrict__ acat, int aggByPath,
    const float* __restrict__ eps0, const float* __restrict__ eps1, int eps_idx,
    const float* __restrict__ W1_0, const float* __restrict__ b1_0,
    const float* __restrict__ W2_0, const float* __restrict__ b2_0,
    const float* __restrict__ W1_1, const float* __restrict__ b1_1,
    const float* __restrict__ W2_1, const float* __restrict__ b2_1,
    bf16_t* __restrict__ out)
{
    __shared__ short sW1t[128 * 136];   // 34.8 KB; y1 overlays after hoist
    __shared__ short sW2t[128 * 136];   // 34.8 KB
    float* y1buf = (float*)sW1t;        // [64][132] f32 = 33.8 KB

    const int p = (blockIdx.x >= NTILES) ? 1 : 0;
    const int t = blockIdx.x - p * NTILES;
    const float* W1 = p ? W1_1 : W1_0;
    const float* b1 = p ? b1_1 : b1_0;
    const float* W2 = p ? W2_1 : W2_0;
    const float* b2 = p ? b2_1 : b2_0;
    const float* epsp = p ? eps1 : eps0;
    const HinT* hbase = (INSTRIDE == 256) ? (hin + p * 128) : hin;
    const float* abase = acat + (aggByPath ? p * 128 : 0);
    bf16_t* ob = out + p * 128;

    const int tid = threadIdx.x;
    // ---- stage W1^T and W2^T (fp32 -> bf16, transpose) ----
    #pragma unroll
    for (int it = 0; it < 8; ++it) {
        int idx = it * 256 + tid;
        int n = idx & 127, koct = idx >> 7;   // k octet
        float f1[8], f2[8];
        #pragma unroll
        for (int j = 0; j < 8; ++j) {
            f1[j] = W1[(8 * koct + j) * 128 + n];
            f2[j] = W2[(8 * koct + j) * 128 + n];
        }
        uint4 u1, u2;
        u1.x = pack2bf(f1[0], f1[1]); u1.y = pack2bf(f1[2], f1[3]);
        u1.z = pack2bf(f1[4], f1[5]); u1.w = pack2bf(f1[6], f1[7]);
        u2.x = pack2bf(f2[0], f2[1]); u2.y = pack2bf(f2[2], f2[3]);
        u2.z = pack2bf(f2[4], f2[5]); u2.w = pack2bf(f2[6], f2[7]);
        *(uint4*)&sW1t[n * 136 + 8 * koct] = u1;
        *(uint4*)&sW2t[n * 136 + 8 * koct] = u2;
    }
    __syncthreads();

    const int lane = tid & 63, w = tid >> 6;
    const int m = lane & 15, quad = lane >> 4;

    // ---- hoist W1 B-fragments to VGPRs ----
    short8 bf1[32];
    #pragma unroll
    for (int c = 0; c < 8; ++c)
        #pragma unroll
        for (int k0 = 0; k0 < 4; ++k0)
            bf1[c * 4 + k0] = *(const short8*)&sW1t[(16 * c + m) * 136 + 32 * k0 + 8 * quad];
    __syncthreads();   // sW1t now free for y1 overlay

    const float scale = 1.0f + epsp[eps_idx];
    float b1v[8], b2v[8];
    #pragma unroll
    for (int c = 0; c < 8; ++c) { b1v[c] = b1[16 * c + m]; b2v[c] = b2[16 * c + m]; }

    const int arow = min(t * 64 + 16 * w + m, NNODES - 1);

    // ---- A-fragments: z = scale*hin + agg, hi/lo split ----
    short8 afh[4], afl[4];
    #pragma unroll
    for (int k0 = 0; k0 < 4; ++k0) {
        const int kb = 32 * k0 + 8 * quad;
        float zf[8];
        if constexpr (sizeof(HinT) == 4) {
            const float* hp = (const float*)hbase + (size_t)arow * INSTRIDE + kb;
            float4 h0 = *(const float4*)hp;
            float4 h1 = *(const float4*)(hp + 4);
            zf[0] = h0.x; zf[1] = h0.y; zf[2] = h0.z; zf[3] = h0.w;
            zf[4] = h1.x; zf[5] = h1.y; zf[6] = h1.z; zf[7] = h1.w;
        } else {
            uint4 hu = *(const uint4*)((const bf16_t*)hbase + (size_t)arow * INSTRIDE + kb);
            zf[0] = bf_lo(hu.x); zf[1] = bf_hi(hu.x);
            zf[2] = bf_lo(hu.y); zf[3] = bf_hi(hu.y);
            zf[4] = bf_lo(hu.z); zf[5] = bf_hi(hu.z);
            zf[6] = bf_lo(hu.w); zf[7] = bf_hi(hu.w);
        }
        const float* ap = abase + (size_t)arow * 256 + kb;
        float4 a0 = *(const float4*)ap;
        float4 a1 = *(const float4*)(ap + 4);
        zf[0] = fmaf(scale, zf[0], a0.x); zf[1] = fmaf(scale, zf[1], a0.y);
        zf[2] = fmaf(scale, zf[2], a0.z); zf[3] = fmaf(scale, zf[3], a0.w);
        zf[4] = fmaf(scale, zf[4], a1.x); zf[5] = fmaf(scale, zf[5], a1.y);
        zf[6] = fmaf(scale, zf[6], a1.z); zf[7] = fmaf(scale, zf[7], a1.w);
        S8U hi;
        hi.us[0] = pack2bf(zf[0], zf[1]); hi.us[1] = pack2bf(zf[2], zf[3]);
        hi.us[2] = pack2bf(zf[4], zf[5]); hi.us[3] = pack2bf(zf[6], zf[7]);
        afh[k0] = hi.v;
        S8U lo;
        float lw[8];
        lw[0] = zf[0] - bf_lo(hi.us[0]); lw[1] = zf[1] - bf_hi(hi.us[0]);
        lw[2] = zf[2] - bf_lo(hi.us[1]); lw[3] = zf[3] - bf_hi(hi.us[1]);
        lw[4] = zf[4] - bf_lo(hi.us[2]); lw[5] = zf[5] - bf_hi(hi.us[2]);
        lw[6] = zf[6] - bf_lo(hi.us[3]); lw[7] = zf[7] - bf_hi(hi.us[3]);
        lo.us[0] = pack2bf(lw[0], lw[1]); lo.us[1] = pack2bf(lw[2], lw[3]);
        lo.us[2] = pack2bf(lw[4], lw[5]); lo.us[3] = pack2bf(lw[6], lw[7]);
        afl[k0] = lo.v;
    }

    // ---- MFMA1 ----
    f32x4 acc[8];
    #pragma unroll
    for (int c = 0; c < 8; ++c) acc[c] = (f32x4){0.f, 0.f, 0.f, 0.f};
    #pragma unroll
    for (int k0 = 0; k0 < 4; ++k0) {
        #pragma unroll
        for (int c = 0; c < 8; ++c)
            acc[c] = __builtin_amdgcn_mfma_f32_16x16x32_bf16(
                afl[k0], bf1[c * 4 + k0], acc[c], 0, 0, 0);
        #pragma unroll
        for (int c = 0; c < 8; ++c)
            acc[c] = __builtin_amdgcn_mfma_f32_16x16x32_bf16(
                afh[k0], bf1[c * 4 + k0], acc[c], 0, 0, 0);
    }

    // ---- sigmoid + stage y1 (f32) into LDS overlay ----
    const int rloc0 = 16 * w + 4 * quad;   // local row in [0,64)
    #pragma unroll
    for (int r = 0; r < 4; ++r) {
        #pragma unroll
        for (int c = 0; c < 8; ++c) {
            float y = acc[c][r] + b1v[c];
            y = 1.0f / (1.0f + expf(-y));
            y1buf[(rloc0 + r) * 132 + 16 * c + m] = y;
        }
    }
    __syncthreads();

    // ---- MFMA2: A from y1buf (pack bf16), B from sW2t ----
    f32x4 acc2[8];
    #pragma unroll
    for (int c = 0; c < 8; ++c) acc2[c] = (f32x4){0.f, 0.f, 0.f, 0.f};
    #pragma unroll
    for (int k0 = 0; k0 < 4; ++k0) {
        const int kb = 32 * k0 + 8 * quad;
        const float* yp = &y1buf[(16 * w + m) * 132 + kb];
        float4 p0 = *(const float4*)yp;
        float4 p1 = *(const float4*)(yp + 4);
        S8U a2;
        a2.us[0] = pack2bf(p0.x, p0.y); a2.us[1] = pack2bf(p0.z, p0.w);
        a2.us[2] = pack2bf(p1.x, p1.y); a2.us[3] = pack2bf(p1.z, p1.w);
        #pragma unroll
        for (int c = 0; c < 8; ++c) {
            short8 b2f = *(const short8*)&sW2t[(16 * c + m) * 136 + kb];
            acc2[c] = __builtin_amdgcn_mfma_f32_16x16x32_bf16(
                a2.v, b2f, acc2[c], 0, 0, 0);
        }
    }

    // ---- epilogue: h_out = acc2 + b2 (bf16, stride 256) ----
    const int row0 = t * 64 + 16 * w + 4 * quad;
    #pragma unroll
    for (int r = 0; r < 4; ++r) {
        const int grow = row0 + r;
        if (grow < NNODES) {
            bf16_t* op = ob + (size_t)grow * 256 + m;
            #pragma unroll
            for (int c = 0; c < 8; ++c) op[16 * c] = f2bf(acc2[c][r] + b2v[c]);
        }
    }
}

// ---------------------------------------------------------------------------
// threefry / normal helpers (eps = jax.random.normal(key(42))).
// ---------------------------------------------------------------------------
__device__ __forceinline__ unsigned rotl32(unsigned x, int r) {
    return (x << r) | (x >> (32 - r));
}

__device__ __forceinline__ unsigned threefry_xor(unsigned c0, unsigned c1) {
    const unsigned k0 = 0u, k1 = 42u;
    const unsigned k2 = k0 ^ k1 ^ 0x1BD11BDAu;
    unsigned x0 = c0 + k0;
    unsigned x1 = c1 + k1;
#define TF_ROUND(R) { x0 += x1; x1 = rotl32(x1, R); x1 ^= x0; }
    TF_ROUND(13) TF_ROUND(15) TF_ROUND(26) TF_ROUND(6)
    x0 += k1; x1 += k2 + 1u;
    TF_ROUND(17) TF_ROUND(29) TF_ROUND(16) TF_ROUND(24)
    x0 += k2; x1 += k0 + 2u;
    TF_ROUND(13) TF_ROUND(15) TF_ROUND(26) TF_ROUND(6)
    x0 += k0; x1 += k1 + 3u;
    TF_ROUND(17) TF_ROUND(29) TF_ROUND(16) TF_ROUND(24)
    x0 += k1; x1 += k2 + 4u;
    TF_ROUND(13) TF_ROUND(15) TF_ROUND(26) TF_ROUND(6)
    x0 += k2; x1 += k0 + 5u;
#undef TF_ROUND
    return x0 ^ x1;
}

__device__ __forceinline__ float bits_to_normal(unsigned bits) {
    float f = __uint_as_float((bits >> 9) | 0x3F800000u) - 1.0f;
    const float lo = -0.99999994f;
    float u = __fadd_rn(__fmul_rn(f, 2.0f), lo);
    u = fmaxf(lo, u);
    float w = -log1pf(-(u * u));
    float p;
    if (w < 5.0f) {
        w -= 2.5f;
        p = 2.81022636e-08f;
        p = fmaf(p, w, 3.43273939e-07f);
        p = fmaf(p, w, -3.5233877e-06f);
        p = fmaf(p, w, -4.39150654e-06f);
        p = fmaf(p, w, 0.00021858087f);
        p = fmaf(p, w, -0.00125372503f);
        p = fmaf(p, w, -0.00417768164f);
        p = fmaf(p, w, 0.246640727f);
        p = fmaf(p, w, 1.50140941f);
    } else {
        w = sqrtf(w) - 3.0f;
        p = -0.000200214257f;
        p = fmaf(p, w, 0.000100950558f);
        p = fmaf(p, w, 0.00134934322f);
        p = fmaf(p, w, -0.00367342844f);
        p = fmaf(p, w, 0.00573950773f);
        p = fmaf(p, w, -0.0076224613f);
        p = fmaf(p, w, 0.00943887047f);
        p = fmaf(p, w, 1.00167406f);
        p = fmaf(p, w, 2.83297682f);
    }
    return 1.41421356f * (p * u);
}

// ---------------------------------------------------------------------------
// FUSED final projection + LN + sampling (both paths per block):
//   mean = LN(h0@Wo0+bo0), std = LN(h1@Wo1+bo1),
//   samples = mean + eps*std.  Writes S (aliases h_cat bytes -> barrier
//   between the block's A-frag loads and any store), M, V.
// ---------------------------------------------------------------------------
__global__ __launch_bounds__(TPB) void final_samples_kernel(
    const bf16_t* __restrict__ hc,
    const float* __restrict__ Wo0, const float* __restrict__ bo0,
    const float* __restrict__ Wo1, const float* __restrict__ bo1,
    const float* __restrict__ gamma, const float* __restrict__ beta,
    float* __restrict__ S, float* __restrict__ M, float* __restrict__ V)
{
    __shared__ short sW0[128 * 136];   // 34.8 KB
    __shared__ short sW1[128 * 136];   // 34.8 KB

    const int tid = threadIdx.x;
    #pragma unroll
    for (int it = 0; it < 8; ++it) {
        int idx = it * 256 + tid;
        int n = idx & 127, koct = idx >> 7;
        float f0[8], f1[8];
        #pragma unroll
        for (int j = 0; j < 8; ++j) {
            f0[j] = Wo0[(8 * koct + j) * 128 + n];
            f1[j] = Wo1[(8 * koct + j) * 128 + n];
        }
        uint4 u0, u1;
        u0.x = pack2bf(f0[0], f0[1]); u0.y = pack2bf(f0[2], f0[3]);
        u0.z = pack2bf(f0[4], f0[5]); u0.w = pack2bf(f0[6], f0[7]);
        u1.x = pack2bf(f1[0], f1[1]); u1.y = pack2bf(f1[2], f1[3]);
        u1.z = pack2bf(f1[4], f1[5]); u1.w = pack2bf(f1[6], f1[7]);
        *(uint4*)&sW0[n * 136 + 8 * koct] = u0;
        *(uint4*)&sW1[n * 136 + 8 * koct] = u1;
    }
    __syncthreads();

    const int lane = tid & 63, w = tid >> 6;
    const int m = lane & 15, quad = lane >> 4;
    const int t = blockIdx.x;
    const int arow = min(t * 64 + 16 * w + m, NNODES - 1);

    // A-frags for both path halves of the 512B h_cat row
    short8 af0[4], af1[4];
    #pragma unroll
    for (int k0 = 0; k0 < 4; ++k0) {
        const bf16_t* hp = hc + (size_t)arow * 256 + 32 * k0 + 8 * quad;
        af0[k0] = *(const short8*)hp;
        af1[k0] = *(const short8*)(hp + 128);
    }
    // all h_cat reads complete before any thread's S write (aliases h_cat)
    __syncthreads();

    float g_v[8], bt_v[8], bias0[8], bias1[8];
    #pragma unroll
    for (int c = 0; c < 8; ++c) {
        g_v[c] = gamma[16 * c + m];
        bt_v[c] = beta[16 * c + m];
        bias0[c] = bo0[16 * c + m];
        bias1[c] = bo1[16 * c + m];
    }

    const int row0 = t * 64 + 16 * w + 4 * quad;
    float y0[4][8], y1[4][8];

    // ---- path 0 GEMM + LN -> y0 ----
    {
        f32x4 acc[8];
        #pragma unroll
        for (int c = 0; c < 8; ++c) acc[c] = (f32x4){0.f, 0.f, 0.f, 0.f};
        #pragma unroll
        for (int k0 = 0; k0 < 4; ++k0) {
            const int kb = 32 * k0 + 8 * quad;
            #pragma unroll
            for (int c = 0; c < 8; ++c)
                acc[c] = __builtin_amdgcn_mfma_f32_16x16x32_bf16(
                    af0[k0], *(const short8*)&sW0[(16 * c + m) * 136 + kb], acc[c], 0, 0, 0);
        }
        #pragma unroll
        for (int r = 0; r < 4; ++r) {
            float y[8];
            #pragma unroll
            for (int c = 0; c < 8; ++c) y[c] = acc[c][r] + bias0[c];
            float s1 = 0.f, s2 = 0.f;
            #pragma unroll
            for (int c = 0; c < 8; ++c) { s1 += y[c]; s2 = fmaf(y[c], y[c], s2); }
            #pragma unroll
            for (int d = 1; d < 16; d <<= 1) { s1 += __shfl_xor(s1, d); s2 += __shfl_xor(s2, d); }
            float mean = s1 * (1.0f / DIM);
            float var  = s2 * (1.0f / DIM) - mean * mean;
            float rstd = rsqrtf(var + 1e-5f);
            #pragma unroll
            for (int c = 0; c < 8; ++c)
                y0[r][c] = fmaf((y[c] - mean) * rstd, g_v[c], bt_v[c]);
        }
    }
    // ---- path 1 GEMM + LN -> y1 ----
    {
        f32x4 acc[8];
        #pragma unroll
        for (int c = 0; c < 8; ++c) acc[c] = (f32x4){0.f, 0.f, 0.f, 0.f};
        #pragma unroll
        for (int k0 = 0; k0 < 4; ++k0) {
            const int kb = 32 * k0 + 8 * quad;
            #pragma unroll
            for (int c = 0; c < 8; ++c)
                acc[c] = __builtin_amdgcn_mfma_f32_16x16x32_bf16(
                    af1[k0], *(const short8*)&sW1[(16 * c + m) * 136 + kb], acc[c], 0, 0, 0);
        }
        #pragma unroll
        for (int r = 0; r < 4; ++r) {
            float y[8];
            #pragma unroll
            for (int c = 0; c < 8; ++c) y[c] = acc[c][r] + bias1[c];
            float s1 = 0.f, s2 = 0.f;
            #pragma unroll
            for (int c = 0; c < 8; ++c) { s1 += y[c]; s2 = fmaf(y[c], y[c], s2); }
            #pragma unroll
            for (int d = 1; d < 16; d <<= 1) { s1 += __shfl_xor(s1, d); s2 += __shfl_xor(s2, d); }
            float mean = s1 * (1.0f / DIM);
            float var  = s2 * (1.0f / DIM) - mean * mean;
            float rstd = rsqrtf(var + 1e-5f);
            #pragma unroll
            for (int c = 0; c < 8; ++c)
                y1[r][c] = fmaf((y[c] - mean) * rstd, g_v[c], bt_v[c]);
        }
    }

    // ---- write M, V, S = M + eps*V ----
    #pragma unroll
    for (int r = 0; r < 4; ++r) {
        const int grow = row0 + r;
        if (grow < NNODES) {
            float* mp = M + (size_t)grow * DIM + m;
            float* vp = V + (size_t)grow * DIM + m;
            float* sp = S + (size_t)grow * DIM + m;
            #pragma unroll
            for (int c = 0; c < 8; ++c) {
                float mv = y0[r][c], sv = y1[r][c];
                mp[16 * c] = mv;
                vp[16 * c] = sv;
                unsigned i = (unsigned)grow * 128u + (unsigned)(16 * c + m);
                float e = bits_to_normal(threefry_xor(0u, i));
                sp[16 * c] = fmaf(e, sv, mv);
            }
        }
    }
}

// ---------------------------------------------------------------------------
// Orchestration (layer-interleaved paths, concatenated h):
//   CSR build -> shared L0 f32 gather (into acat mean-half) ->
//   fused0 (both paths, x -> h_cat) ->
//   [gather_cat -> fused_l (both paths)] x2 -> final+samples. 12 dispatches.
//   Buffers: h_cat = S (25.6MB bf16), acat = M..V (51.2MB f32, dead before
//   final writes M/V), samples overwrite h_cat bytes in S (block-private).
//   d_ws: gcnt[196] | start[197] | bcur[196] | off[50001] | bucket[NE].
// ---------------------------------------------------------------------------
extern "C" void kernel_launch(void* const* d_in, const int* in_sizes, int n_in,
                              void* d_out, int out_size, void* d_ws, size_t ws_size,
                              hipStream_t stream)
{
    const float* x     = (const float*)d_in[0];
    const int*   esrc  = (const int*)d_in[1];
    const int*   edst  = (const int*)d_in[2];
    const float* prm[2][7];
    for (int p = 0; p < 2; p++)
        for (int i = 0; i < 7; i++)
            prm[p][i] = (const float*)d_in[3 + p * 7 + i];
    const float* gamma = (const float*)d_in[17];
    const float* beta  = (const float*)d_in[18];

    float*  S  = (float*)d_out;
    float*  M  = S + NHID;
    float*  V  = M + NHID;
    bf16_t* Hc = (bf16_t*)S;     // h_cat [50000][256] bf16 = 25.6 MB
    float*  ACAT = M;            // [50000][256] f32 spans M..V = 51.2 MB

    int* gcnt  = (int*)d_ws;                       // NBINS
    int* start = gcnt + NBINS;                     // NBINS + 1
    int* bcur  = start + NBINS + 1;                // NBINS
    int* off   = bcur + NBINS;                     // NNODES + 1
    unsigned* bucket = (unsigned*)(off + NNODES + 1);  // NEDGES

    const dim3 gChunk(NCHUNKS);
    const dim3 gBin(NBINS);
    const dim3 gGather((NNODES + (TPB / 64) - 1) / (TPB / 64));
    const dim3 gTile2(2 * NTILES);
    const dim3 gTile(NTILES);

    hipMemsetAsync(gcnt, 0, NBINS * sizeof(int), stream);
    bin_hist_kernel<<<gChunk, TPB, 0, stream>>>(edst, gcnt);
    bin_scan_kernel<<<1, 64, 0, stream>>>(gcnt, start, bcur, off);
    bin_scatter_kernel<<<gChunk, TPB, 0, stream>>>(esrc, edst, bcur, bucket);
    build_csr_kernel<<<gBin, TPB, 0, stream>>>(start, bucket, off);

    // shared layer-0 aggregation (fp32 x) -> acat mean-half
    gather_agg_f32_kernel<<<gGather, TPB, 0, stream>>>(x, off, bucket, ACAT);

    // layer 0, both paths: z = (1+eps)*x + agg0 -> h_cat halves
    fused_layer_kernel<float, DIM><<<gTile2, TPB, 0, stream>>>(
        x, ACAT, 0, prm[0][4], prm[1][4], 0,
        prm[0][0], prm[0][1], prm[0][2], prm[0][3],
        prm[1][0], prm[1][1], prm[1][2], prm[1][3], Hc);

    for (int l = 1; l < 3; l++) {
        gather_cat_kernel<<<gGather, TPB, 0, stream>>>(Hc, off, bucket, ACAT);
        fused_layer_kernel<bf16_t, 256><<<gTile2, TPB, 0, stream>>>(
            Hc, ACAT, 1, prm[0][4], prm[1][4], l,
            prm[0][0] + (size_t)l * DIM * DIM, prm[0][1] + l * DIM,
            prm[0][2] + (size_t)l * DIM * DIM, prm[0][3] + l * DIM,
            prm[1][0] + (size_t)l * DIM * DIM, prm[1][1] + l * DIM,
            prm[1][2] + (size_t)l * DIM * DIM, prm[1][3] + l * DIM, Hc);
    }

    final_samples_kernel<<<gTile, TPB, 0, stream>>>(
        Hc, prm[0][5], prm[0][6], prm[1][5], prm[1][6], gamma, beta, S, M, V);
}

// Round 7
// 644.165 us; speedup vs baseline: 1.0843x; 1.0843x over previous
//
#include <hip/hip_runtime.h>
#include <math.h>

#define NNODES 50000
#define NEDGES 1600000
#define DIM    128
#define NHID   (NNODES * DIM)      // 6,400,000
#define TPB    256
#define NTILES ((NNODES + 63) / 64)   // 782, 64 rows per block-tile

// binned CSR build
#define NBINS  196                 // ceil(50000/256)
#define BINSZ  256                 // nodes per bin (dst>>8)
#define EPT    16                  // edges per thread in binning passes
#define CHUNK  (TPB * EPT)         // 4096 edges per block
#define NCHUNKS ((NEDGES + CHUNK - 1) / CHUNK)   // 391
#define BINCAP 10240               // staged edges per bin (mean 8192, sigma 90)

typedef unsigned short bf16_t;
typedef __attribute__((ext_vector_type(8))) short short8;   // 8 bf16, 4 VGPRs
typedef __attribute__((ext_vector_type(4))) float f32x4;    // MFMA acc

__device__ __forceinline__ float bf_lo(unsigned u) { return __uint_as_float(u << 16); }
__device__ __forceinline__ float bf_hi(unsigned u) { return __uint_as_float(u & 0xFFFF0000u); }
__device__ __forceinline__ bf16_t f2bf(float f) {   // RNE
    unsigned u = __float_as_uint(f);
    u += 0x7FFFu + ((u >> 16) & 1u);
    return (bf16_t)(u >> 16);
}
__device__ __forceinline__ unsigned pack2bf(float a, float b) {
    return (unsigned)f2bf(a) | ((unsigned)f2bf(b) << 16);
}

union S8U { short8 v; uint4 u4; unsigned us[4]; };

// ===========================================================================
// CSR build, dense-write pipeline (round-2 proven):
//   bin_hist -> bin_scan -> bin_scatter (packed dl<<16|src) -> build_csr
//   (per-bin LDS counting sort -> per-node off[] + sorted src bucket).
// ===========================================================================
__global__ __launch_bounds__(TPB) void bin_hist_kernel(
    const int* __restrict__ dst, int* __restrict__ gcnt)
{
    __shared__ int lcnt[NBINS];
    const int tid = threadIdx.x;
    for (int i = tid; i < NBINS; i += TPB) lcnt[i] = 0;
    __syncthreads();
    const int base = blockIdx.x * CHUNK;
    #pragma unroll
    for (int k = 0; k < EPT; ++k) {
        int e = base + k * TPB + tid;
        if (e < NEDGES) atomicAdd(&lcnt[dst[e] >> 8], 1);
    }
    __syncthreads();
    for (int i = tid; i < NBINS; i += TPB) {
        int c = lcnt[i];
        if (c) atomicAdd(&gcnt[i], c);
    }
}

__global__ __launch_bounds__(64) void bin_scan_kernel(
    const int* __restrict__ gcnt, int* __restrict__ start, int* __restrict__ bcur,
    int* __restrict__ off)
{
    const int lane = threadIdx.x;   // 64 lanes, each owns 4 bins
    int c[4];
    int s = 0;
    #pragma unroll
    for (int k = 0; k < 4; ++k) {
        int b = 4 * lane + k;
        c[k] = (b < NBINS) ? gcnt[b] : 0;
        s += c[k];
    }
    int incl = s;
    #pragma unroll
    for (int d = 1; d < 64; d <<= 1) {
        int t = __shfl_up(incl, d);
        if (lane >= d) incl += t;
    }
    int excl = incl - s;
    #pragma unroll
    for (int k = 0; k < 4; ++k) {
        int b = 4 * lane + k;
        if (b < NBINS) { start[b] = excl; bcur[b] = excl; }
        excl += c[k];
    }
    if (lane == 63) { start[NBINS] = excl; off[NNODES] = excl; }   // == NEDGES
}

__global__ __launch_bounds__(TPB) void bin_scatter_kernel(
    const int* __restrict__ src, const int* __restrict__ dst,
    int* __restrict__ bcur, unsigned* __restrict__ bucket)
{
    __shared__ int lcnt[NBINS];    // phase A: counts
    __shared__ int lcur[NBINS];    // phase C: absolute cursors
    const int tid = threadIdx.x;
    for (int i = tid; i < NBINS; i += TPB) lcnt[i] = 0;
    __syncthreads();

    unsigned pk[EPT];
    int bn[EPT];
    const int base = blockIdx.x * CHUNK;
    #pragma unroll
    for (int k = 0; k < EPT; ++k) {
        int e = base + k * TPB + tid;
        int b = -1; unsigned p = 0;
        if (e < NEDGES) {
            int d = dst[e];
            int s = src[e];
            b = d >> 8;
            p = ((unsigned)(d & 255) << 16) | (unsigned)s;
            atomicAdd(&lcnt[b], 1);
        }
        pk[k] = p; bn[k] = b;
    }
    __syncthreads();
    for (int i = tid; i < NBINS; i += TPB) {
        int c = lcnt[i];
        lcur[i] = (c > 0) ? atomicAdd(&bcur[i], c) : 0;
    }
    __syncthreads();
    #pragma unroll
    for (int k = 0; k < EPT; ++k) {
        if (bn[k] >= 0) {
            int p = atomicAdd(&lcur[bn[k]], 1);
            bucket[p] = pk[k];
        }
    }
}

__global__ __launch_bounds__(TPB) void build_csr_kernel(
    const int* __restrict__ start, unsigned* __restrict__ bucket,
    int* __restrict__ off)
{
    __shared__ unsigned se[BINCAP];   // staged bin edges, 40 KB
    __shared__ int lcnt[BINSZ];
    __shared__ int lofs[BINSZ];
    __shared__ int wsum[4];
    const int tid = threadIdx.x;
    const int b = blockIdx.x;
    const int j0 = start[b], j1 = start[b + 1];
    const int n = j1 - j0;            // <= BINCAP by construction

    lcnt[tid] = 0;
    for (int i = tid; i < n; i += TPB) se[i] = bucket[j0 + i];
    __syncthreads();
    for (int i = tid; i < n; i += TPB) atomicAdd(&lcnt[se[i] >> 16], 1);
    __syncthreads();

    // exclusive scan of lcnt[256] across 4 waves
    const int lane = tid & 63, wid = tid >> 6;
    int v = lcnt[tid];
    int s = v;
    #pragma unroll
    for (int d = 1; d < 64; d <<= 1) {
        int t = __shfl_up(s, d);
        if (lane >= d) s += t;
    }
    if (lane == 63) wsum[wid] = s;
    __syncthreads();
    if (tid == 0) {
        int a = 0;
        #pragma unroll
        for (int k = 0; k < 4; ++k) { int t = wsum[k]; wsum[k] = a; a += t; }
    }
    __syncthreads();
    int excl = wsum[wid] + s - v;
    lofs[tid] = excl;
    int node = b * BINSZ + tid;
    if (node < NNODES) off[node] = j0 + excl;
    __syncthreads();

    // in-place counting-sort scatter (safe: all edges staged in LDS)
    for (int i = tid; i < n; i += TPB) {
        unsigned e = se[i];
        int pos = atomicAdd(&lofs[e >> 16], 1);
        bucket[j0 + pos] = e & 0xFFFFu;   // src node id
    }
}

// ---------------------------------------------------------------------------
// Gather aggregation, wave per node, 16/8/1-deep ILP. gather_cat reads the
// full contiguous 512B h_cat row with ONE wave-wide uint2 load (lanes 0-31
// mean half, 32-63 std half); float4 store at 4*lane maps to [mean|std].
// ---------------------------------------------------------------------------
__global__ __launch_bounds__(TPB) void gather_agg_f32_kernel(
    const float* __restrict__ h, const int* __restrict__ off,
    const unsigned* __restrict__ bucket, float* __restrict__ acat)
{
    int node = blockIdx.x * (TPB / 64) + (threadIdx.x >> 6);
    int lane = threadIdx.x & 63;
    if (node >= NNODES) return;
    int j0 = off[node], j1 = off[node + 1];
    const float* base = h + 2 * lane;
    float ax = 0.0f, ay = 0.0f;
    int j = j0;
    for (; j + 16 <= j1; j += 16) {
        unsigned s[16];
        #pragma unroll
        for (int k = 0; k < 16; ++k) s[k] = bucket[j + k];
        float2 v[16];
        #pragma unroll
        for (int k = 0; k < 16; ++k) v[k] = *(const float2*)(base + (size_t)s[k] * DIM);
        #pragma unroll
        for (int k = 0; k < 16; ++k) { ax += v[k].x; ay += v[k].y; }
    }
    for (; j + 8 <= j1; j += 8) {
        unsigned s[8];
        #pragma unroll
        for (int k = 0; k < 8; ++k) s[k] = bucket[j + k];
        float2 v[8];
        #pragma unroll
        for (int k = 0; k < 8; ++k) v[k] = *(const float2*)(base + (size_t)s[k] * DIM);
        #pragma unroll
        for (int k = 0; k < 8; ++k) { ax += v[k].x; ay += v[k].y; }
    }
    for (; j < j1; ++j) {
        float2 v0 = *(const float2*)(base + (size_t)bucket[j] * DIM);
        ax += v0.x; ay += v0.y;
    }
    *(float2*)(acat + (size_t)node * 256 + 2 * lane) = make_float2(ax, ay);
}

__global__ __launch_bounds__(TPB) void gather_cat_kernel(
    const bf16_t* __restrict__ hc, const int* __restrict__ off,
    const unsigned* __restrict__ bucket, float* __restrict__ acat)
{
    int node = blockIdx.x * (TPB / 64) + (threadIdx.x >> 6);
    int lane = threadIdx.x & 63;
    if (node >= NNODES) return;
    int j0 = off[node], j1 = off[node + 1];
    const uint2* base = (const uint2*)hc + lane;   // 64 uint2 per 512B row
    float a0 = 0.f, a1 = 0.f, a2 = 0.f, a3 = 0.f;
    int j = j0;
    for (; j + 16 <= j1; j += 16) {
        unsigned s[16];
        #pragma unroll
        for (int k = 0; k < 16; ++k) s[k] = bucket[j + k];
        uint2 u[16];
        #pragma unroll
        for (int k = 0; k < 16; ++k) u[k] = base[(size_t)s[k] * 64];
        #pragma unroll
        for (int k = 0; k < 16; ++k) {
            a0 += bf_lo(u[k].x); a1 += bf_hi(u[k].x);
            a2 += bf_lo(u[k].y); a3 += bf_hi(u[k].y);
        }
    }
    for (; j + 8 <= j1; j += 8) {
        unsigned s[8];
        #pragma unroll
        for (int k = 0; k < 8; ++k) s[k] = bucket[j + k];
        uint2 u[8];
        #pragma unroll
        for (int k = 0; k < 8; ++k) u[k] = base[(size_t)s[k] * 64];
        #pragma unroll
        for (int k = 0; k < 8; ++k) {
            a0 += bf_lo(u[k].x); a1 += bf_hi(u[k].x);
            a2 += bf_lo(u[k].y); a3 += bf_hi(u[k].y);
        }
    }
    for (; j < j1; ++j) {
        uint2 u = base[(size_t)bucket[j] * 64];
        a0 += bf_lo(u.x); a1 += bf_hi(u.x);
        a2 += bf_lo(u.y); a3 += bf_hi(u.y);
    }
    // lane<32: mean cols 4l..4l+3 -> acat[4l..]; lane>=32: std cols -> 128+...
    *(float4*)(acat + (size_t)node * 256 + 4 * lane) = make_float4(a0, a1, a2, a3);
}

// ---------------------------------------------------------------------------
// FUSED GIN layer v2, both paths in one grid (block path = blockIdx/NTILES):
//   out_half = sigmoid(z@W1+b1)@W2+b2, z = (1+eps)*hin_half + agg_half.
//   Occupancy-first: ONE W LDS buffer (W1 then W2, 34.8 KB) + bf16 y1
//   (17.4 KB) = 52.2 KB -> 3 blocks/CU; no VGPR W-hoist, B-frags read from
//   LDS in both MFMA phases; __launch_bounds__(TPB,4) caps VGPR at 128 ->
//   12 waves/CU (was 8). y1 stored bf16 via f2bf = same RNE point as the
//   old f32-store+pack-at-read -> bit-identical numerics. In-place safe.
// ---------------------------------------------------------------------------
template <class HinT, int INSTRIDE>
__global__ __launch_bounds__(TPB, 4) void fused_layer_kernel(
    const HinT* __restrict__ hin, const float* __restrict__ acat, int aggByPath,
    const float* __restrict__ eps0, const float* __restrict__ eps1, int eps_idx,
    const float* __restrict__ W1_0, const float* __restrict__ b1_0,
    const float* __restrict__ W2_0, const float* __restrict__ b2_0,
    const float* __restrict__ W1_1, const float* __restrict__ b1_1,
    const float* __restrict__ W2_1, const float* __restrict__ b2_1,
    bf16_t* __restrict__ out)
{
    __shared__ short sWt[128 * 136];   // 34.8 KB: W1^T, then W2^T
    __shared__ short y1b[64 * 136];    // 17.4 KB: bf16 y1

    const int p = (blockIdx.x >= NTILES) ? 1 : 0;
    const int t = blockIdx.x - p * NTILES;
    const float* W1 = p ? W1_1 : W1_0;
    const float* b1 = p ? b1_1 : b1_0;
    const float* W2 = p ? W2_1 : W2_0;
    const float* b2 = p ? b2_1 : b2_0;
    const float* epsp = p ? eps1 : eps0;
    const HinT* hbase = (INSTRIDE == 256) ? (hin + p * 128) : hin;
    const float* abase = acat + (aggByPath ? p * 128 : 0);
    bf16_t* ob = out + p * 128;

    const int tid = threadIdx.x;
    // ---- stage W1^T (fp32 -> bf16, transpose) ----
    #pragma unroll
    for (int it = 0; it < 8; ++it) {
        int idx = it * 256 + tid;
        int n = idx & 127, koct = idx >> 7;   // k octet
        float f1[8];
        #pragma unroll
        for (int j = 0; j < 8; ++j) f1[j] = W1[(8 * koct + j) * 128 + n];
        uint4 u1;
        u1.x = pack2bf(f1[0], f1[1]); u1.y = pack2bf(f1[2], f1[3]);
        u1.z = pack2bf(f1[4], f1[5]); u1.w = pack2bf(f1[6], f1[7]);
        *(uint4*)&sWt[n * 136 + 8 * koct] = u1;
    }
    __syncthreads();

    const int lane = tid & 63, w = tid >> 6;
    const int m = lane & 15, quad = lane >> 4;

    const float scale = 1.0f + epsp[eps_idx];
    float b1v[8], b2v[8];
    #pragma unroll
    for (int c = 0; c < 8; ++c) { b1v[c] = b1[16 * c + m]; b2v[c] = b2[16 * c + m]; }

    const int arow = min(t * 64 + 16 * w + m, NNODES - 1);

    // ---- A-fragments: z = scale*hin + agg, hi/lo split ----
    short8 afh[4], afl[4];
    #pragma unroll
    for (int k0 = 0; k0 < 4; ++k0) {
        const int kb = 32 * k0 + 8 * quad;
        float zf[8];
        if constexpr (sizeof(HinT) == 4) {
            const float* hp = (const float*)hbase + (size_t)arow * INSTRIDE + kb;
            float4 h0 = *(const float4*)hp;
            float4 h1 = *(const float4*)(hp + 4);
            zf[0] = h0.x; zf[1] = h0.y; zf[2] = h0.z; zf[3] = h0.w;
            zf[4] = h1.x; zf[5] = h1.y; zf[6] = h1.z; zf[7] = h1.w;
        } else {
            uint4 hu = *(const uint4*)((const bf16_t*)hbase + (size_t)arow * INSTRIDE + kb);
            zf[0] = bf_lo(hu.x); zf[1] = bf_hi(hu.x);
            zf[2] = bf_lo(hu.y); zf[3] = bf_hi(hu.y);
            zf[4] = bf_lo(hu.z); zf[5] = bf_hi(hu.z);
            zf[6] = bf_lo(hu.w); zf[7] = bf_hi(hu.w);
        }
        const float* ap = abase + (size_t)arow * 256 + kb;
        float4 a0 = *(const float4*)ap;
        float4 a1 = *(const float4*)(ap + 4);
        zf[0] = fmaf(scale, zf[0], a0.x); zf[1] = fmaf(scale, zf[1], a0.y);
        zf[2] = fmaf(scale, zf[2], a0.z); zf[3] = fmaf(scale, zf[3], a0.w);
        zf[4] = fmaf(scale, zf[4], a1.x); zf[5] = fmaf(scale, zf[5], a1.y);
        zf[6] = fmaf(scale, zf[6], a1.z); zf[7] = fmaf(scale, zf[7], a1.w);
        S8U hi;
        hi.us[0] = pack2bf(zf[0], zf[1]); hi.us[1] = pack2bf(zf[2], zf[3]);
        hi.us[2] = pack2bf(zf[4], zf[5]); hi.us[3] = pack2bf(zf[6], zf[7]);
        afh[k0] = hi.v;
        S8U lo;
        float lw[8];
        lw[0] = zf[0] - bf_lo(hi.us[0]); lw[1] = zf[1] - bf_hi(hi.us[0]);
        lw[2] = zf[2] - bf_lo(hi.us[1]); lw[3] = zf[3] - bf_hi(hi.us[1]);
        lw[4] = zf[4] - bf_lo(hi.us[2]); lw[5] = zf[5] - bf_hi(hi.us[2]);
        lw[6] = zf[6] - bf_lo(hi.us[3]); lw[7] = zf[7] - bf_hi(hi.us[3]);
        lo.us[0] = pack2bf(lw[0], lw[1]); lo.us[1] = pack2bf(lw[2], lw[3]);
        lo.us[2] = pack2bf(lw[4], lw[5]); lo.us[3] = pack2bf(lw[6], lw[7]);
        afl[k0] = lo.v;
    }

    // ---- MFMA1: B-frags from LDS (read once per (k0,c), used twice) ----
    f32x4 acc[8];
    #pragma unroll
    for (int c = 0; c < 8; ++c) acc[c] = (f32x4){0.f, 0.f, 0.f, 0.f};
    #pragma unroll
    for (int k0 = 0; k0 < 4; ++k0) {
        const int kb = 32 * k0 + 8 * quad;
        #pragma unroll
        for (int c = 0; c < 8; ++c) {
            short8 bfr = *(const short8*)&sWt[(16 * c + m) * 136 + kb];
            acc[c] = __builtin_amdgcn_mfma_f32_16x16x32_bf16(afl[k0], bfr, acc[c], 0, 0, 0);
            acc[c] = __builtin_amdgcn_mfma_f32_16x16x32_bf16(afh[k0], bfr, acc[c], 0, 0, 0);
        }
    }

    // ---- sigmoid + stage y1 as bf16 (separate LDS buffer) ----
    const int rloc0 = 16 * w + 4 * quad;   // local row in [0,64)
    #pragma unroll
    for (int r = 0; r < 4; ++r) {
        #pragma unroll
        for (int c = 0; c < 8; ++c) {
            float y = acc[c][r] + b1v[c];
            y = 1.0f / (1.0f + expf(-y));
            y1b[(rloc0 + r) * 136 + 16 * c + m] = (short)f2bf(y);
        }
    }
    __syncthreads();   // MFMA1 sWt reads + y1 writes complete

    // ---- stage W2^T into the same buffer ----
    #pragma unroll
    for (int it = 0; it < 8; ++it) {
        int idx = it * 256 + tid;
        int n = idx & 127, koct = idx >> 7;
        float f2[8];
        #pragma unroll
        for (int j = 0; j < 8; ++j) f2[j] = W2[(8 * koct + j) * 128 + n];
        uint4 u2;
        u2.x = pack2bf(f2[0], f2[1]); u2.y = pack2bf(f2[2], f2[3]);
        u2.z = pack2bf(f2[4], f2[5]); u2.w = pack2bf(f2[6], f2[7]);
        *(uint4*)&sWt[n * 136 + 8 * koct] = u2;
    }
    __syncthreads();

    // ---- MFMA2: A from y1b (bf16 direct), B from sWt ----
    f32x4 acc2[8];
    #pragma unroll
    for (int c = 0; c < 8; ++c) acc2[c] = (f32x4){0.f, 0.f, 0.f, 0.f};
    #pragma unroll
    for (int k0 = 0; k0 < 4; ++k0) {
        const int kb = 32 * k0 + 8 * quad;
        short8 a2 = *(const short8*)&y1b[(16 * w + m) * 136 + kb];
        #pragma unroll
        for (int c = 0; c < 8; ++c) {
            short8 b2f = *(const short8*)&sWt[(16 * c + m) * 136 + kb];
            acc2[c] = __builtin_amdgcn_mfma_f32_16x16x32_bf16(a2, b2f, acc2[c], 0, 0, 0);
        }
    }

    // ---- epilogue: h_out = acc2 + b2 (bf16, stride 256) ----
    const int row0 = t * 64 + 16 * w + 4 * quad;
    #pragma unroll
    for (int r = 0; r < 4; ++r) {
        const int grow = row0 + r;
        if (grow < NNODES) {
            bf16_t* op = ob + (size_t)grow * 256 + m;
            #pragma unroll
            for (int c = 0; c < 8; ++c) op[16 * c] = f2bf(acc2[c][r] + b2v[c]);
        }
    }
}

// ---------------------------------------------------------------------------
// Final projection + layernorm, both paths in one grid (round-5 proven):
//   out(p) = layernorm(h_cat(p) @ Wout + bout) * gamma + beta  (fp32)
// ---------------------------------------------------------------------------
__global__ __launch_bounds__(TPB) void final_proj_kernel(
    const bf16_t* __restrict__ hc,
    const float* __restrict__ Wo0, const float* __restrict__ bo0,
    const float* __restrict__ Wo1, const float* __restrict__ bo1,
    const float* __restrict__ gamma, const float* __restrict__ beta,
    float* __restrict__ M, float* __restrict__ V)
{
    __shared__ short sWt[128 * 136];   // bf16 W^T

    const int p = (blockIdx.x >= NTILES) ? 1 : 0;
    const int t = blockIdx.x - p * NTILES;
    const float* W = p ? Wo1 : Wo0;
    const float* bias = p ? bo1 : bo0;
    const bf16_t* hbase = hc + p * 128;
    float* out = p ? V : M;

    const int tid = threadIdx.x;
    #pragma unroll
    for (int it = 0; it < 8; ++it) {
        int idx = it * 256 + tid;
        int n = idx & 127, koct = idx >> 7;
        float f[8];
        #pragma unroll
        for (int j = 0; j < 8; ++j) f[j] = W[(8 * koct + j) * 128 + n];
        uint4 u;
        u.x = pack2bf(f[0], f[1]); u.y = pack2bf(f[2], f[3]);
        u.z = pack2bf(f[4], f[5]); u.w = pack2bf(f[6], f[7]);
        *(uint4*)&sWt[n * 136 + 8 * koct] = u;
    }
    __syncthreads();

    const int lane = tid & 63, w = tid >> 6;
    const int m = lane & 15, quad = lane >> 4;

    short8 bf[32];
    #pragma unroll
    for (int c = 0; c < 8; ++c)
        #pragma unroll
        for (int k0 = 0; k0 < 4; ++k0)
            bf[c * 4 + k0] = *(const short8*)&sWt[(16 * c + m) * 136 + 32 * k0 + 8 * quad];

    float bias_v[8], g_v[8], bt_v[8];
    #pragma unroll
    for (int c = 0; c < 8; ++c) {
        bias_v[c] = bias[16 * c + m];
        g_v[c] = gamma[16 * c + m];
        bt_v[c] = beta[16 * c + m];
    }

    const int arow = min(t * 64 + 16 * w + m, NNODES - 1);
    short8 af[4];
    #pragma unroll
    for (int k0 = 0; k0 < 4; ++k0)
        af[k0] = *(const short8*)(hbase + (size_t)arow * 256 + 32 * k0 + 8 * quad);

    f32x4 acc[8];
    #pragma unroll
    for (int c = 0; c < 8; ++c) acc[c] = (f32x4){0.f, 0.f, 0.f, 0.f};
    #pragma unroll
    for (int k0 = 0; k0 < 4; ++k0)
        #pragma unroll
        for (int c = 0; c < 8; ++c)
            acc[c] = __builtin_amdgcn_mfma_f32_16x16x32_bf16(
                af[k0], bf[c * 4 + k0], acc[c], 0, 0, 0);

    const int row0 = t * 64 + 16 * w + 4 * quad;
    #pragma unroll
    for (int r = 0; r < 4; ++r) {
        const int grow = row0 + r;
        float y[8];
        #pragma unroll
        for (int c = 0; c < 8; ++c) y[c] = acc[c][r] + bias_v[c];
        float s1 = 0.f, s2 = 0.f;
        #pragma unroll
        for (int c = 0; c < 8; ++c) { s1 += y[c]; s2 = fmaf(y[c], y[c], s2); }
        #pragma unroll
        for (int d = 1; d < 16; d <<= 1) {
            s1 += __shfl_xor(s1, d);
            s2 += __shfl_xor(s2, d);
        }
        float mean = s1 * (1.0f / DIM);
        float var  = s2 * (1.0f / DIM) - mean * mean;
        float rstd = rsqrtf(var + 1e-5f);
        if (grow < NNODES) {
            float* op = out + (size_t)grow * DIM + m;
            #pragma unroll
            for (int c = 0; c < 8; ++c)
                op[16 * c] = fmaf((y[c] - mean) * rstd, g_v[c], bt_v[c]);
        }
    }
}

// ---------------------------------------------------------------------------
// samples = mean + eps*std; eps = jax.random.normal(key(42)), partitionable
// threefry: block inputs (0, i), bits = out0 ^ out1, key (0,42).
// ---------------------------------------------------------------------------
__device__ __forceinline__ unsigned rotl32(unsigned x, int r) {
    return (x << r) | (x >> (32 - r));
}

__device__ __forceinline__ unsigned threefry_xor(unsigned c0, unsigned c1) {
    const unsigned k0 = 0u, k1 = 42u;
    const unsigned k2 = k0 ^ k1 ^ 0x1BD11BDAu;
    unsigned x0 = c0 + k0;
    unsigned x1 = c1 + k1;
#define TF_ROUND(R) { x0 += x1; x1 = rotl32(x1, R); x1 ^= x0; }
    TF_ROUND(13) TF_ROUND(15) TF_ROUND(26) TF_ROUND(6)
    x0 += k1; x1 += k2 + 1u;
    TF_ROUND(17) TF_ROUND(29) TF_ROUND(16) TF_ROUND(24)
    x0 += k2; x1 += k0 + 2u;
    TF_ROUND(13) TF_ROUND(15) TF_ROUND(26) TF_ROUND(6)
    x0 += k0; x1 += k1 + 3u;
    TF_ROUND(17) TF_ROUND(29) TF_ROUND(16) TF_ROUND(24)
    x0 += k1; x1 += k2 + 4u;
    TF_ROUND(13) TF_ROUND(15) TF_ROUND(26) TF_ROUND(6)
    x0 += k2; x1 += k0 + 5u;
#undef TF_ROUND
    return x0 ^ x1;
}

__device__ __forceinline__ float bits_to_normal(unsigned bits) {
    float f = __uint_as_float((bits >> 9) | 0x3F800000u) - 1.0f;
    const float lo = -0.99999994f;
    float u = __fadd_rn(__fmul_rn(f, 2.0f), lo);
    u = fmaxf(lo, u);
    float w = -log1pf(-(u * u));
    float p;
    if (w < 5.0f) {
        w -= 2.5f;
        p = 2.81022636e-08f;
        p = fmaf(p, w, 3.43273939e-07f);
        p = fmaf(p, w, -3.5233877e-06f);
        p = fmaf(p, w, -4.39150654e-06f);
        p = fmaf(p, w, 0.00021858087f);
        p = fmaf(p, w, -0.00125372503f);
        p = fmaf(p, w, -0.00417768164f);
        p = fmaf(p, w, 0.246640727f);
        p = fmaf(p, w, 1.50140941f);
    } else {
        w = sqrtf(w) - 3.0f;
        p = -0.000200214257f;
        p = fmaf(p, w, 0.000100950558f);
        p = fmaf(p, w, 0.00134934322f);
        p = fmaf(p, w, -0.00367342844f);
        p = fmaf(p, w, 0.00573950773f);
        p = fmaf(p, w, -0.0076224613f);
        p = fmaf(p, w, 0.00943887047f);
        p = fmaf(p, w, 1.00167406f);
        p = fmaf(p, w, 2.83297682f);
    }
    return 1.41421356f * (p * u);
}

__global__ __launch_bounds__(TPB) void samples_kernel(
    const float* __restrict__ mean_v, const float* __restrict__ std_v,
    float* __restrict__ samples)
{
    int t = blockIdx.x * TPB + threadIdx.x;
    if (t >= NHID / 4) return;
    float4 m = ((const float4*)mean_v)[t];
    float4 s = ((const float4*)std_v)[t];
    float e[4];
    #pragma unroll
    for (int q = 0; q < 4; q++) {
        unsigned i = 4u * (unsigned)t + (unsigned)q;
        e[q] = bits_to_normal(threefry_xor(0u, i));
    }
    float4 r;
    r.x = fmaf(e[0], s.x, m.x);
    r.y = fmaf(e[1], s.y, m.y);
    r.z = fmaf(e[2], s.z, m.z);
    r.w = fmaf(e[3], s.w, m.w);
    ((float4*)samples)[t] = r;
}

// ---------------------------------------------------------------------------
// Orchestration (layer-interleaved paths, concatenated h):
//   CSR build -> shared L0 f32 gather (into acat mean-half) ->
//   fused0 (both paths, x -> h_cat) ->
//   [gather_cat -> fused_l (both paths)] x2 -> final_proj -> samples.
//   13 dispatches. Buffers: h_cat = S (25.6MB bf16), acat = M..V (51.2MB
//   f32, dead before final writes M/V), samples -> S (h_cat dead).
//   d_ws: gcnt[196] | start[197] | bcur[196] | off[50001] | bucket[NE].
// ---------------------------------------------------------------------------
extern "C" void kernel_launch(void* const* d_in, const int* in_sizes, int n_in,
                              void* d_out, int out_size, void* d_ws, size_t ws_size,
                              hipStream_t stream)
{
    const float* x     = (const float*)d_in[0];
    const int*   esrc  = (const int*)d_in[1];
    const int*   edst  = (const int*)d_in[2];
    const float* prm[2][7];
    for (int p = 0; p < 2; p++)
        for (int i = 0; i < 7; i++)
            prm[p][i] = (const float*)d_in[3 + p * 7 + i];
    const float* gamma = (const float*)d_in[17];
    const float* beta  = (const float*)d_in[18];

    float*  S  = (float*)d_out;
    float*  M  = S + NHID;
    float*  V  = M + NHID;
    bf16_t* Hc = (bf16_t*)S;     // h_cat [50000][256] bf16 = 25.6 MB
    float*  ACAT = M;            // [50000][256] f32 spans M..V = 51.2 MB

    int* gcnt  = (int*)d_ws;                       // NBINS
    int* start = gcnt + NBINS;                     // NBINS + 1
    int* bcur  = start + NBINS + 1;                // NBINS
    int* off   = bcur + NBINS;                     // NNODES + 1
    unsigned* bucket = (unsigned*)(off + NNODES + 1);  // NEDGES

    const dim3 gChunk(NCHUNKS);
    const dim3 gBin(NBINS);
    const dim3 gGather((NNODES + (TPB / 64) - 1) / (TPB / 64));
    const dim3 gTile2(2 * NTILES);
    const dim3 gSamp((NHID / 4 + TPB - 1) / TPB);

    hipMemsetAsync(gcnt, 0, NBINS * sizeof(int), stream);
    bin_hist_kernel<<<gChunk, TPB, 0, stream>>>(edst, gcnt);
    bin_scan_kernel<<<1, 64, 0, stream>>>(gcnt, start, bcur, off);
    bin_scatter_kernel<<<gChunk, TPB, 0, stream>>>(esrc, edst, bcur, bucket);
    build_csr_kernel<<<gBin, TPB, 0, stream>>>(start, bucket, off);

    // shared layer-0 aggregation (fp32 x) -> acat mean-half
    gather_agg_f32_kernel<<<gGather, TPB, 0, stream>>>(x, off, bucket, ACAT);

    // layer 0, both paths: z = (1+eps)*x + agg0 -> h_cat halves
    fused_layer_kernel<float, DIM><<<gTile2, TPB, 0, stream>>>(
        x, ACAT, 0, prm[0][4], prm[1][4], 0,
        prm[0][0], prm[0][1], prm[0][2], prm[0][3],
        prm[1][0], prm[1][1], prm[1][2], prm[1][3], Hc);

    for (int l = 1; l < 3; l++) {
        gather_cat_kernel<<<gGather, TPB, 0, stream>>>(Hc, off, bucket, ACAT);
        fused_layer_kernel<bf16_t, 256><<<gTile2, TPB, 0, stream>>>(
            Hc, ACAT, 1, prm[0][4], prm[1][4], l,
            prm[0][0] + (size_t)l * DIM * DIM, prm[0][1] + l * DIM,
            prm[0][2] + (size_t)l * DIM * DIM, prm[0][3] + l * DIM,
            prm[1][0] + (size_t)l * DIM * DIM, prm[1][1] + l * DIM,
            prm[1][2] + (size_t)l * DIM * DIM, prm[1][3] + l * DIM, Hc);
    }

    final_proj_kernel<<<gTile2, TPB, 0, stream>>>(
        Hc, prm[0][5], prm[0][6], prm[1][5], prm[1][6], gamma, beta, M, V);

    samples_kernel<<<gSamp, TPB, 0, stream>>>(M, V, S);
}